// Round 17
// baseline (154.333 us; speedup 1.0000x reference)
//
#include <hip/hip_runtime.h>
#include <hip/hip_bf16.h>

#define IN_CH 64
#define HC 128          // HEADS * OUT_CH
#define HEADS 8
#define OUT_CH 16
#define NEG 0.2f

#define BK_BITS 8
#define BK_SIZE 256     // nodes per bucket
#define BK_CAP 5120     // padded capacity (mean 4092, 16-sigma margin)
#define BIN_CHUNK 2048  // edges per bin block (782 blocks: 2x latency hiding)
#define PROJ_TPB 4      // 64-row tiles per proj block (amortize fragment staging)

typedef __attribute__((ext_vector_type(8))) short short8;
typedef __attribute__((ext_vector_type(4))) float f32x4;

__device__ __forceinline__ float lrelu(float x) {
    return fmaxf(x, NEG * x);   // valid for NEG<1
}
__device__ __forceinline__ short f2bf(float f) {
    __hip_bfloat16 b = __float2bfloat16(f);
    return *(short*)&b;
}

// ---- bin: edges -> padded bucket regions, packed src|(dlow<<17) ----
__global__ __launch_bounds__(256) void bin_kernel(
    const int* __restrict__ ei, int E, int nbuck,
    int* __restrict__ cursor, unsigned* __restrict__ binned)
{
    __shared__ int cnt[512];
    __shared__ int resv[512];
    int tid = threadIdx.x;
    int chunk0 = blockIdx.x * BIN_CHUNK;
    for (int i = tid; i < nbuck; i += 256) cnt[i] = 0;
    __syncthreads();
    for (int i = tid; i < BIN_CHUNK; i += 256) {
        int e = chunk0 + i;
        if (e < E) atomicAdd(&cnt[ei[E + e] >> BK_BITS], 1);
    }
    __syncthreads();
    for (int i = tid; i < nbuck; i += 256)
        if (cnt[i]) resv[i] = i * BK_CAP + atomicAdd(&cursor[i], cnt[i]);
    __syncthreads();
    for (int i = tid; i < BIN_CHUNK; i += 256) {
        int e = chunk0 + i;
        if (e < E) {
            int s = ei[e], d = ei[E + e];
            int b = d >> BK_BITS;
            int p = atomicAdd(&resv[b], 1);
            binned[p] = (unsigned)s | ((unsigned)(d & (BK_SIZE - 1)) << 17);
        }
    }
}

// ---- fused: blocks [0,nbuck) build CSR (dep: bin only); rest do MFMA proj
//      with 4 row-tiles per block (fragment staging amortized 4x). ----
__global__ __launch_bounds__(256) void fused_proj_b4(
    const float* __restrict__ x, const float* __restrict__ W,
    const float* __restrict__ att_src, const float* __restrict__ att_dst,
    __hip_bfloat16* __restrict__ hb, float* __restrict__ asrc,
    float* __restrict__ adst, int n,
    const unsigned* __restrict__ binned, const int* __restrict__ cursor,
    int2* __restrict__ row2, int* __restrict__ csr, int nbuck)
{
    __shared__ float sh[1024];   // b4: deg[256]+ts[256]; proj: wa[64][16]
    int tid = threadIdx.x;

    if ((int)blockIdx.x < nbuck) {
        // ---- b4 body: 256-node bucket, 256-wide scan ----
        int* deg = (int*)sh;
        int* ts  = (int*)sh + 256;
        int b = blockIdx.x;
        int node0 = b << BK_BITS;
        int nn = min(BK_SIZE, n - node0);
        int e0 = b * BK_CAP;
        int e1 = e0 + cursor[b];        // cursor holds bucket count

        deg[tid] = 0;
        __syncthreads();
        for (int j = e0 + tid; j < e1; j += 256)
            atomicAdd(&deg[binned[j] >> 17], 1);
        __syncthreads();

        int v = deg[tid];
        ts[tid] = v;
        __syncthreads();
        for (int o = 1; o < 256; o <<= 1) {
            int xv = (tid >= o) ? ts[tid - o] : 0;
            __syncthreads();
            ts[tid] += xv;
            __syncthreads();
        }
        int excl = ts[tid] - v;
        if (tid < nn) row2[node0 + tid] = make_int2(e0 + excl, e0 + excl + v);
        __syncthreads();
        deg[tid] = excl;                // per-node scatter cursor
        __syncthreads();
        for (int j = e0 + tid; j < e1; j += 256) {
            unsigned pk = binned[j];
            int dl = pk >> 17;
            int s = (int)(pk & 0x1FFFFu);
            int p = atomicAdd(&deg[dl], 1);
            csr[e0 + p] = s;
        }
        return;
    }

    // ---- proj body: stage fragments once, loop 4 row-tiles ----
    for (int idx = tid; idx < IN_CH * 16; idx += 256) {
        int k = idx >> 4, i = idx & 15;
        const float* av = (i < 8) ? att_src : att_dst;
        int hd = (i < 8) ? i : i - 8;
        float s = 0.f;
        #pragma unroll
        for (int c = 0; c < 16; ++c)
            s += W[k * HC + hd * 16 + c] * av[hd * 16 + c];
        sh[idx] = s;
    }
    __syncthreads();

    int lane = threadIdx.x & 63;
    int w    = threadIdx.x >> 6;
    int m    = lane & 15;     // A-row / B-col / D-col
    int kg   = lane >> 4;     // k-group

    short8 bf[9][2];
    #pragma unroll
    for (int s = 0; s < 2; ++s) {
        #pragma unroll
        for (int t = 0; t < 8; ++t) {
            #pragma unroll
            for (int j = 0; j < 8; ++j) {
                int k = s * 32 + kg * 8 + j;
                bf[t][s][j] = f2bf(W[k * HC + t * 16 + m]);
            }
        }
        #pragma unroll
        for (int j = 0; j < 8; ++j) {
            int k = s * 32 + kg * 8 + j;
            bf[8][s][j] = f2bf(sh[k * 16 + m]);
        }
    }

    int base = ((int)blockIdx.x - nbuck) * (64 * PROJ_TPB);

    #pragma unroll
    for (int tt = 0; tt < PROJ_TPB; ++tt) {
        int rowbase = base + tt * 64 + w * 16;
        if (rowbase >= n) break;

        int rowc = min(rowbase + m, n - 1);
        const float* xp = x + (long long)rowc * IN_CH + kg * 8;
        short8 af[2];
        #pragma unroll
        for (int s = 0; s < 2; ++s) {
            float4 f0 = *(const float4*)(xp + s * 32);
            float4 f1 = *(const float4*)(xp + s * 32 + 4);
            af[s][0] = f2bf(f0.x); af[s][1] = f2bf(f0.y);
            af[s][2] = f2bf(f0.z); af[s][3] = f2bf(f0.w);
            af[s][4] = f2bf(f1.x); af[s][5] = f2bf(f1.y);
            af[s][6] = f2bf(f1.z); af[s][7] = f2bf(f1.w);
        }

        f32x4 acc[9];
        #pragma unroll
        for (int t = 0; t < 9; ++t) acc[t] = (f32x4){0.f, 0.f, 0.f, 0.f};

        #pragma unroll
        for (int s = 0; s < 2; ++s)
            #pragma unroll
            for (int t = 0; t < 9; ++t)
                acc[t] = __builtin_amdgcn_mfma_f32_16x16x32_bf16(
                             af[s], bf[t][s], acc[t], 0, 0, 0);

        #pragma unroll
        for (int r = 0; r < 4; ++r) {
            int orow = rowbase + kg * 4 + r;
            if (orow < n) {
                __hip_bfloat16* hp = hb + (long long)orow * HC + m;
                #pragma unroll
                for (int t = 0; t < 8; ++t)
                    hp[t * 16] = __float2bfloat16(acc[t][r]);
                float av = acc[8][r];
                if (m < 8) asrc[orow * HEADS + m] = av;
                else       adst[orow * HEADS + (m - 8)] = av;
            }
        }
    }
}

// ---- fused softmax + aggregation: own-head exp, unroll-8 (87.3us floor,
// untouched) ----
__global__ __launch_bounds__(256) void agg_kernel(
    const int* __restrict__ csr, const int2* __restrict__ row2,
    const float* __restrict__ asrc, const float* __restrict__ adst,
    const __hip_bfloat16* __restrict__ hb, const float* __restrict__ bias,
    float* __restrict__ out, int n)
{
    int wave = threadIdx.x >> 6;
    int lane = threadIdx.x & 63;
    int d = blockIdx.x * 4 + wave;
    if (d >= n) return;

    int hO = lane >> 3;         // head owning this lane's output cols

    int2 se = row2[d];
    int start = se.x, end = se.y;

    float adstv = adst[d * HEADS + hO];
    const unsigned* hu = (const unsigned*)hb;

    // self loop
    float w = __expf(lrelu(asrc[d * HEADS + hO] + adstv));
    unsigned u = hu[(long long)d * 64 + lane];
    float denom = w;
    float accx = w * __uint_as_float(u << 16);
    float accy = w * __uint_as_float(u & 0xFFFF0000u);

    int j = start;
    for (; j + 7 < end; j += 8) {
        int s0 = csr[j],     s1 = csr[j + 1], s2 = csr[j + 2], s3 = csr[j + 3];
        int s4 = csr[j + 4], s5 = csr[j + 5], s6 = csr[j + 6], s7 = csr[j + 7];
        float w0 = __expf(lrelu(asrc[s0 * HEADS + hO] + adstv));
        float w1 = __expf(lrelu(asrc[s1 * HEADS + hO] + adstv));
        float w2 = __expf(lrelu(asrc[s2 * HEADS + hO] + adstv));
        float w3 = __expf(lrelu(asrc[s3 * HEADS + hO] + adstv));
        float w4 = __expf(lrelu(asrc[s4 * HEADS + hO] + adstv));
        float w5 = __expf(lrelu(asrc[s5 * HEADS + hO] + adstv));
        float w6 = __expf(lrelu(asrc[s6 * HEADS + hO] + adstv));
        float w7 = __expf(lrelu(asrc[s7 * HEADS + hO] + adstv));
        unsigned u0 = hu[(long long)s0 * 64 + lane];
        unsigned u1 = hu[(long long)s1 * 64 + lane];
        unsigned u2 = hu[(long long)s2 * 64 + lane];
        unsigned u3 = hu[(long long)s3 * 64 + lane];
        unsigned u4 = hu[(long long)s4 * 64 + lane];
        unsigned u5 = hu[(long long)s5 * 64 + lane];
        unsigned u6 = hu[(long long)s6 * 64 + lane];
        unsigned u7 = hu[(long long)s7 * 64 + lane];
        denom += ((w0 + w1) + (w2 + w3)) + ((w4 + w5) + (w6 + w7));
        accx = fmaf(w0, __uint_as_float(u0 << 16), accx);
        accy = fmaf(w0, __uint_as_float(u0 & 0xFFFF0000u), accy);
        accx = fmaf(w1, __uint_as_float(u1 << 16), accx);
        accy = fmaf(w1, __uint_as_float(u1 & 0xFFFF0000u), accy);
        accx = fmaf(w2, __uint_as_float(u2 << 16), accx);
        accy = fmaf(w2, __uint_as_float(u2 & 0xFFFF0000u), accy);
        accx = fmaf(w3, __uint_as_float(u3 << 16), accx);
        accy = fmaf(w3, __uint_as_float(u3 & 0xFFFF0000u), accy);
        accx = fmaf(w4, __uint_as_float(u4 << 16), accx);
        accy = fmaf(w4, __uint_as_float(u4 & 0xFFFF0000u), accy);
        accx = fmaf(w5, __uint_as_float(u5 << 16), accx);
        accy = fmaf(w5, __uint_as_float(u5 & 0xFFFF0000u), accy);
        accx = fmaf(w6, __uint_as_float(u6 << 16), accx);
        accy = fmaf(w6, __uint_as_float(u6 & 0xFFFF0000u), accy);
        accx = fmaf(w7, __uint_as_float(u7 << 16), accx);
        accy = fmaf(w7, __uint_as_float(u7 & 0xFFFF0000u), accy);
    }
    for (; j + 3 < end; j += 4) {
        int s0 = csr[j], s1 = csr[j + 1], s2 = csr[j + 2], s3 = csr[j + 3];
        float w0 = __expf(lrelu(asrc[s0 * HEADS + hO] + adstv));
        float w1 = __expf(lrelu(asrc[s1 * HEADS + hO] + adstv));
        float w2 = __expf(lrelu(asrc[s2 * HEADS + hO] + adstv));
        float w3 = __expf(lrelu(asrc[s3 * HEADS + hO] + adstv));
        unsigned u0 = hu[(long long)s0 * 64 + lane];
        unsigned u1 = hu[(long long)s1 * 64 + lane];
        unsigned u2 = hu[(long long)s2 * 64 + lane];
        unsigned u3 = hu[(long long)s3 * 64 + lane];
        denom += (w0 + w1) + (w2 + w3);
        accx = fmaf(w0, __uint_as_float(u0 << 16), accx);
        accy = fmaf(w0, __uint_as_float(u0 & 0xFFFF0000u), accy);
        accx = fmaf(w1, __uint_as_float(u1 << 16), accx);
        accy = fmaf(w1, __uint_as_float(u1 & 0xFFFF0000u), accy);
        accx = fmaf(w2, __uint_as_float(u2 << 16), accx);
        accy = fmaf(w2, __uint_as_float(u2 & 0xFFFF0000u), accy);
        accx = fmaf(w3, __uint_as_float(u3 << 16), accx);
        accy = fmaf(w3, __uint_as_float(u3 & 0xFFFF0000u), accy);
    }
    for (; j < end; ++j) {
        int s0 = csr[j];
        float w0 = __expf(lrelu(asrc[s0 * HEADS + hO] + adstv));
        unsigned u0 = hu[(long long)s0 * 64 + lane];
        denom += w0;
        accx = fmaf(w0, __uint_as_float(u0 << 16), accx);
        accy = fmaf(w0, __uint_as_float(u0 & 0xFFFF0000u), accy);
    }

    float inv = 1.f / (denom + 1e-16f);
    const float2* b2 = (const float2*)bias;
    float2 bb = b2[lane];
    float2 o;
    o.x = fmaxf(fmaf(accx, inv, bb.x), 0.f);
    o.y = fmaxf(fmaf(accy, inv, bb.y), 0.f);
    ((float2*)out)[(long long)d * 64 + lane] = o;
}

extern "C" void kernel_launch(void* const* d_in, const int* in_sizes, int n_in,
                              void* d_out, int out_size, void* d_ws, size_t ws_size,
                              hipStream_t stream) {
    const float* x       = (const float*)d_in[0];
    const float* W       = (const float*)d_in[1];
    const float* att_src = (const float*)d_in[2];
    const float* att_dst = (const float*)d_in[3];
    const float* bias    = (const float*)d_in[4];
    const int*   ei      = (const int*)d_in[5];

    int n = in_sizes[0] / IN_CH;        // 100000
    int E = in_sizes[5] / 2;            // 1600000
    float* out = (float*)d_out;
    int nbuck = (n + BK_SIZE - 1) >> BK_BITS;   // 391 (<=512 required)

    // workspace layout
    char* ws = (char*)d_ws;
    __hip_bfloat16* hb = (__hip_bfloat16*)ws; ws += (size_t)n * HC * 2;  // 25.6 MB
    float* asrc = (float*)ws;   ws += (size_t)n * HEADS * 4;             // 3.2 MB
    float* adst = (float*)ws;   ws += (size_t)n * HEADS * 4;             // 3.2 MB
    int*   csr  = (int*)ws;     ws += ((size_t)nbuck * BK_CAP + 64) * 4; // 8.0 MB
    unsigned* binned = (unsigned*)ws; ws += (size_t)nbuck * BK_CAP * 4;  // 8.0 MB
    int2*  row2 = (int2*)ws;    ws += (size_t)n * 8;                     // 0.8 MB
    int*   cursor=(int*)ws;     ws += 512 * 4;

    hipMemsetAsync(cursor, 0, 512 * 4, stream);

    int nbin = (E + BIN_CHUNK - 1) / BIN_CHUNK;     // 782
    bin_kernel<<<nbin, 256, 0, stream>>>(ei, E, nbuck, cursor, binned);

    int pblk = (n + 64 * PROJ_TPB - 1) / (64 * PROJ_TPB);   // 391
    fused_proj_b4<<<nbuck + pblk, 256, 0, stream>>>(
        x, W, att_src, att_dst, hb, asrc, adst, n,
        binned, cursor, row2, csr, nbuck);

    int ablk = (n + 3) / 4;
    agg_kernel<<<ablk, 256, 0, stream>>>(csr, row2, asrc, adst, hb, bias, out, n);
}

// Round 18
// 148.418 us; speedup vs baseline: 1.0399x; 1.0399x over previous
//
#include <hip/hip_runtime.h>
#include <hip/hip_bf16.h>

#define IN_CH 64
#define HC 128          // HEADS * OUT_CH
#define HEADS 8
#define OUT_CH 16
#define NEG 0.2f

#define BK_BITS 8
#define BK_SIZE 256     // nodes per bucket
#define BK_CAP 5120     // padded capacity (mean 4092, 16-sigma margin)
#define BIN_CHUNK 4096  // edges per bin block

typedef __attribute__((ext_vector_type(8))) short short8;
typedef __attribute__((ext_vector_type(4))) float f32x4;

__device__ __forceinline__ float lrelu(float x) {
    return fmaxf(x, NEG * x);   // valid for NEG<1
}
__device__ __forceinline__ short f2bf(float f) {
    __hip_bfloat16 b = __float2bfloat16(f);
    return *(short*)&b;
}

// ---- bin: edges -> padded bucket regions, packed src|(dlow<<17) ----
// (src < 2^17; dlow = d & 255 in bits 17..24)
__global__ __launch_bounds__(256) void bin_kernel(
    const int* __restrict__ ei, int E, int nbuck,
    int* __restrict__ cursor, unsigned* __restrict__ binned)
{
    __shared__ int cnt[512];
    __shared__ int resv[512];
    int tid = threadIdx.x;
    int chunk0 = blockIdx.x * BIN_CHUNK;
    for (int i = tid; i < nbuck; i += 256) cnt[i] = 0;
    __syncthreads();
    for (int i = tid; i < BIN_CHUNK; i += 256) {
        int e = chunk0 + i;
        if (e < E) atomicAdd(&cnt[ei[E + e] >> BK_BITS], 1);
    }
    __syncthreads();
    for (int i = tid; i < nbuck; i += 256)
        if (cnt[i]) resv[i] = i * BK_CAP + atomicAdd(&cursor[i], cnt[i]);
    __syncthreads();
    for (int i = tid; i < BIN_CHUNK; i += 256) {
        int e = chunk0 + i;
        if (e < E) {
            int s = ei[e], d = ei[E + e];
            int b = d >> BK_BITS;
            int p = atomicAdd(&resv[b], 1);
            binned[p] = (unsigned)s | ((unsigned)(d & (BK_SIZE - 1)) << 17);
        }
    }
}

// ---- fused: blocks [0,nbuck) build CSR for bucket b (dep: bin only);
//      blocks [nbuck,..) do MFMA proj (independent). b4 hides under proj. ----
__global__ __launch_bounds__(256) void fused_proj_b4(
    const float* __restrict__ x, const float* __restrict__ W,
    const float* __restrict__ att_src, const float* __restrict__ att_dst,
    __hip_bfloat16* __restrict__ hb, float* __restrict__ asrc,
    float* __restrict__ adst, int n,
    const unsigned* __restrict__ binned, const int* __restrict__ cursor,
    int2* __restrict__ row2, int* __restrict__ csr, int nbuck)
{
    __shared__ float sh[1024];   // b4: deg[256]+ts[256]; proj: wa[64][16]
    int tid = threadIdx.x;

    if ((int)blockIdx.x < nbuck) {
        // ---- b4 body: 256-node bucket, 256-wide scan ----
        int* deg = (int*)sh;
        int* ts  = (int*)sh + 256;
        int b = blockIdx.x;
        int node0 = b << BK_BITS;
        int nn = min(BK_SIZE, n - node0);
        int e0 = b * BK_CAP;
        int e1 = e0 + cursor[b];        // cursor holds bucket count

        deg[tid] = 0;
        __syncthreads();
        for (int j = e0 + tid; j < e1; j += 256)
            atomicAdd(&deg[binned[j] >> 17], 1);
        __syncthreads();

        int v = deg[tid];
        ts[tid] = v;
        __syncthreads();
        for (int o = 1; o < 256; o <<= 1) {
            int xv = (tid >= o) ? ts[tid - o] : 0;
            __syncthreads();
            ts[tid] += xv;
            __syncthreads();
        }
        int excl = ts[tid] - v;
        if (tid < nn) row2[node0 + tid] = make_int2(e0 + excl, e0 + excl + v);
        __syncthreads();
        deg[tid] = excl;                // per-node scatter cursor
        __syncthreads();
        for (int j = e0 + tid; j < e1; j += 256) {
            unsigned pk = binned[j];
            int dl = pk >> 17;
            int s = (int)(pk & 0x1FFFFu);
            int p = atomicAdd(&deg[dl], 1);
            csr[e0 + p] = s;
        }
        return;
    }

    // ---- proj body ----
    for (int idx = tid; idx < IN_CH * 16; idx += 256) {
        int k = idx >> 4, i = idx & 15;
        const float* av = (i < 8) ? att_src : att_dst;
        int hd = (i < 8) ? i : i - 8;
        float s = 0.f;
        #pragma unroll
        for (int c = 0; c < 16; ++c)
            s += W[k * HC + hd * 16 + c] * av[hd * 16 + c];
        sh[idx] = s;
    }
    __syncthreads();

    int lane = threadIdx.x & 63;
    int w    = threadIdx.x >> 6;
    int m    = lane & 15;     // A-row / B-col / D-col
    int kg   = lane >> 4;     // k-group

    int rowbase = ((int)blockIdx.x - nbuck) * 64 + w * 16;

    short8 bf[9][2];
    #pragma unroll
    for (int s = 0; s < 2; ++s) {
        #pragma unroll
        for (int t = 0; t < 8; ++t) {
            #pragma unroll
            for (int j = 0; j < 8; ++j) {
                int k = s * 32 + kg * 8 + j;
                bf[t][s][j] = f2bf(W[k * HC + t * 16 + m]);
            }
        }
        #pragma unroll
        for (int j = 0; j < 8; ++j) {
            int k = s * 32 + kg * 8 + j;
            bf[8][s][j] = f2bf(sh[k * 16 + m]);
        }
    }

    int rowc = min(rowbase + m, n - 1);
    const float* xp = x + (long long)rowc * IN_CH + kg * 8;
    short8 af[2];
    #pragma unroll
    for (int s = 0; s < 2; ++s) {
        float4 f0 = *(const float4*)(xp + s * 32);
        float4 f1 = *(const float4*)(xp + s * 32 + 4);
        af[s][0] = f2bf(f0.x); af[s][1] = f2bf(f0.y);
        af[s][2] = f2bf(f0.z); af[s][3] = f2bf(f0.w);
        af[s][4] = f2bf(f1.x); af[s][5] = f2bf(f1.y);
        af[s][6] = f2bf(f1.z); af[s][7] = f2bf(f1.w);
    }

    f32x4 acc[9];
    #pragma unroll
    for (int t = 0; t < 9; ++t) acc[t] = (f32x4){0.f, 0.f, 0.f, 0.f};

    #pragma unroll
    for (int s = 0; s < 2; ++s)
        #pragma unroll
        for (int t = 0; t < 9; ++t)
            acc[t] = __builtin_amdgcn_mfma_f32_16x16x32_bf16(
                         af[s], bf[t][s], acc[t], 0, 0, 0);

    #pragma unroll
    for (int r = 0; r < 4; ++r) {
        int orow = rowbase + kg * 4 + r;
        if (orow < n) {
            __hip_bfloat16* hp = hb + (long long)orow * HC + m;
            #pragma unroll
            for (int t = 0; t < 8; ++t)
                hp[t * 16] = __float2bfloat16(acc[t][r]);
            float av = acc[8][r];
            if (m < 8) asrc[orow * HEADS + m] = av;
            else       adst[orow * HEADS + (m - 8)] = av;
        }
    }
}

// ---- fused softmax + aggregation: own-head exp, unroll-8 (87.3us floor,
// untouched) ----
__global__ __launch_bounds__(256) void agg_kernel(
    const int* __restrict__ csr, const int2* __restrict__ row2,
    const float* __restrict__ asrc, const float* __restrict__ adst,
    const __hip_bfloat16* __restrict__ hb, const float* __restrict__ bias,
    float* __restrict__ out, int n)
{
    int wave = threadIdx.x >> 6;
    int lane = threadIdx.x & 63;
    int d = blockIdx.x * 4 + wave;
    if (d >= n) return;

    int hO = lane >> 3;         // head owning this lane's output cols

    int2 se = row2[d];
    int start = se.x, end = se.y;

    float adstv = adst[d * HEADS + hO];
    const unsigned* hu = (const unsigned*)hb;

    // self loop
    float w = __expf(lrelu(asrc[d * HEADS + hO] + adstv));
    unsigned u = hu[(long long)d * 64 + lane];
    float denom = w;
    float accx = w * __uint_as_float(u << 16);
    float accy = w * __uint_as_float(u & 0xFFFF0000u);

    int j = start;
    for (; j + 7 < end; j += 8) {
        int s0 = csr[j],     s1 = csr[j + 1], s2 = csr[j + 2], s3 = csr[j + 3];
        int s4 = csr[j + 4], s5 = csr[j + 5], s6 = csr[j + 6], s7 = csr[j + 7];
        float w0 = __expf(lrelu(asrc[s0 * HEADS + hO] + adstv));
        float w1 = __expf(lrelu(asrc[s1 * HEADS + hO] + adstv));
        float w2 = __expf(lrelu(asrc[s2 * HEADS + hO] + adstv));
        float w3 = __expf(lrelu(asrc[s3 * HEADS + hO] + adstv));
        float w4 = __expf(lrelu(asrc[s4 * HEADS + hO] + adstv));
        float w5 = __expf(lrelu(asrc[s5 * HEADS + hO] + adstv));
        float w6 = __expf(lrelu(asrc[s6 * HEADS + hO] + adstv));
        float w7 = __expf(lrelu(asrc[s7 * HEADS + hO] + adstv));
        unsigned u0 = hu[(long long)s0 * 64 + lane];
        unsigned u1 = hu[(long long)s1 * 64 + lane];
        unsigned u2 = hu[(long long)s2 * 64 + lane];
        unsigned u3 = hu[(long long)s3 * 64 + lane];
        unsigned u4 = hu[(long long)s4 * 64 + lane];
        unsigned u5 = hu[(long long)s5 * 64 + lane];
        unsigned u6 = hu[(long long)s6 * 64 + lane];
        unsigned u7 = hu[(long long)s7 * 64 + lane];
        denom += ((w0 + w1) + (w2 + w3)) + ((w4 + w5) + (w6 + w7));
        accx = fmaf(w0, __uint_as_float(u0 << 16), accx);
        accy = fmaf(w0, __uint_as_float(u0 & 0xFFFF0000u), accy);
        accx = fmaf(w1, __uint_as_float(u1 << 16), accx);
        accy = fmaf(w1, __uint_as_float(u1 & 0xFFFF0000u), accy);
        accx = fmaf(w2, __uint_as_float(u2 << 16), accx);
        accy = fmaf(w2, __uint_as_float(u2 & 0xFFFF0000u), accy);
        accx = fmaf(w3, __uint_as_float(u3 << 16), accx);
        accy = fmaf(w3, __uint_as_float(u3 & 0xFFFF0000u), accy);
        accx = fmaf(w4, __uint_as_float(u4 << 16), accx);
        accy = fmaf(w4, __uint_as_float(u4 & 0xFFFF0000u), accy);
        accx = fmaf(w5, __uint_as_float(u5 << 16), accx);
        accy = fmaf(w5, __uint_as_float(u5 & 0xFFFF0000u), accy);
        accx = fmaf(w6, __uint_as_float(u6 << 16), accx);
        accy = fmaf(w6, __uint_as_float(u6 & 0xFFFF0000u), accy);
        accx = fmaf(w7, __uint_as_float(u7 << 16), accx);
        accy = fmaf(w7, __uint_as_float(u7 & 0xFFFF0000u), accy);
    }
    for (; j + 3 < end; j += 4) {
        int s0 = csr[j], s1 = csr[j + 1], s2 = csr[j + 2], s3 = csr[j + 3];
        float w0 = __expf(lrelu(asrc[s0 * HEADS + hO] + adstv));
        float w1 = __expf(lrelu(asrc[s1 * HEADS + hO] + adstv));
        float w2 = __expf(lrelu(asrc[s2 * HEADS + hO] + adstv));
        float w3 = __expf(lrelu(asrc[s3 * HEADS + hO] + adstv));
        unsigned u0 = hu[(long long)s0 * 64 + lane];
        unsigned u1 = hu[(long long)s1 * 64 + lane];
        unsigned u2 = hu[(long long)s2 * 64 + lane];
        unsigned u3 = hu[(long long)s3 * 64 + lane];
        denom += (w0 + w1) + (w2 + w3);
        accx = fmaf(w0, __uint_as_float(u0 << 16), accx);
        accy = fmaf(w0, __uint_as_float(u0 & 0xFFFF0000u), accy);
        accx = fmaf(w1, __uint_as_float(u1 << 16), accx);
        accy = fmaf(w1, __uint_as_float(u1 & 0xFFFF0000u), accy);
        accx = fmaf(w2, __uint_as_float(u2 << 16), accx);
        accy = fmaf(w2, __uint_as_float(u2 & 0xFFFF0000u), accy);
        accx = fmaf(w3, __uint_as_float(u3 << 16), accx);
        accy = fmaf(w3, __uint_as_float(u3 & 0xFFFF0000u), accy);
    }
    for (; j < end; ++j) {
        int s0 = csr[j];
        float w0 = __expf(lrelu(asrc[s0 * HEADS + hO] + adstv));
        unsigned u0 = hu[(long long)s0 * 64 + lane];
        denom += w0;
        accx = fmaf(w0, __uint_as_float(u0 << 16), accx);
        accy = fmaf(w0, __uint_as_float(u0 & 0xFFFF0000u), accy);
    }

    float inv = 1.f / (denom + 1e-16f);
    const float2* b2 = (const float2*)bias;
    float2 bb = b2[lane];
    float2 o;
    o.x = fmaxf(fmaf(accx, inv, bb.x), 0.f);
    o.y = fmaxf(fmaf(accy, inv, bb.y), 0.f);
    ((float2*)out)[(long long)d * 64 + lane] = o;
}

extern "C" void kernel_launch(void* const* d_in, const int* in_sizes, int n_in,
                              void* d_out, int out_size, void* d_ws, size_t ws_size,
                              hipStream_t stream) {
    const float* x       = (const float*)d_in[0];
    const float* W       = (const float*)d_in[1];
    const float* att_src = (const float*)d_in[2];
    const float* att_dst = (const float*)d_in[3];
    const float* bias    = (const float*)d_in[4];
    const int*   ei      = (const int*)d_in[5];

    int n = in_sizes[0] / IN_CH;        // 100000
    int E = in_sizes[5] / 2;            // 1600000
    float* out = (float*)d_out;
    int nbuck = (n + BK_SIZE - 1) >> BK_BITS;   // 391 (<=512 required)

    // workspace layout
    char* ws = (char*)d_ws;
    __hip_bfloat16* hb = (__hip_bfloat16*)ws; ws += (size_t)n * HC * 2;  // 25.6 MB
    float* asrc = (float*)ws;   ws += (size_t)n * HEADS * 4;             // 3.2 MB
    float* adst = (float*)ws;   ws += (size_t)n * HEADS * 4;             // 3.2 MB
    int*   csr  = (int*)ws;     ws += ((size_t)nbuck * BK_CAP + 64) * 4; // 8.0 MB
    unsigned* binned = (unsigned*)ws; ws += (size_t)nbuck * BK_CAP * 4;  // 8.0 MB
    int2*  row2 = (int2*)ws;    ws += (size_t)n * 8;                     // 0.8 MB
    int*   cursor=(int*)ws;     ws += 512 * 4;

    hipMemsetAsync(cursor, 0, 512 * 4, stream);

    int nbin = (E + BIN_CHUNK - 1) / BIN_CHUNK;     // 391
    bin_kernel<<<nbin, 256, 0, stream>>>(ei, E, nbuck, cursor, binned);

    int pblk = (n + 63) / 64;                       // 1563
    fused_proj_b4<<<nbuck + pblk, 256, 0, stream>>>(
        x, W, att_src, att_dst, hb, asrc, adst, n,
        binned, cursor, row2, csr, nbuck);

    int ablk = (n + 3) / 4;
    agg_kernel<<<ablk, 256, 0, stream>>>(csr, row2, asrc, adst, hb, bias, out, n);
}